// Round 1
// baseline (256.512 us; speedup 1.0000x reference)
//
#include <hip/hip_runtime.h>

#define N_NODES 50000
#define D 128
#define N_EDGES 400000
#define NCHUNKS ((N_NODES + 255) / 256)   // 196
#define NBLK32 ((N_NODES + 31) / 32)      // 1563
#define W_FRAG_SHORTS 16384               // 32 frags * 64 lanes * 8 bf16 per weight

#define MW_BLOCKS  64                     // 8 weights * 8 slot-blocks
#define HIST_BLOCKS ((N_EDGES + 255) / 256)   // 1563
#define PREP_BLOCKS (MW_BLOCKS + HIST_BLOCKS)

typedef short s8v  __attribute__((ext_vector_type(8)));   // 8 bf16 (4 VGPRs)
typedef float f4v  __attribute__((ext_vector_type(4)));   // MFMA accumulator

__device__ __forceinline__ unsigned int f2bf(float f) {
    unsigned int u = __float_as_uint(f);
    u += 0x7FFFu + ((u >> 16) & 1u);
    return u >> 16;
}
__device__ __forceinline__ unsigned int packbf(float a, float b) {
    return (f2bf(b) << 16) | f2bf(a);
}
__device__ __forceinline__ float bflo(unsigned int u) { return __uint_as_float(u << 16); }
__device__ __forceinline__ float bfhi(unsigned int u) { return __uint_as_float(u & 0xFFFF0000u); }
__device__ __forceinline__ float sigm(float x) {
    return __builtin_amdgcn_rcpf(1.f + __expf(-x));   // v_rcp_f32, ~1 ulp
}

// ---------------------------------------------------------------------------
// Prep: [0,MW) weight frags | [MW, ...) tgt histogram.
// Wt layout per weight: frag = ntile*4 + kc (ntile 0..7, kc 0..3), 64 lanes,
// 8 bf16 per lane -> slot = frag*64 + lane, stored at Wt[w*16384 + slot*8].
// This is exactly the MFMA B-fragment per-lane layout, so GEMM waves can load
// B straight from global (L2-resident) without any LDS staging.
// ---------------------------------------------------------------------------
__global__ __launch_bounds__(256)
void prep_all(const float* __restrict__ W0, const float* __restrict__ W1,
              const float* __restrict__ W2, const float* __restrict__ W3,
              const float* __restrict__ W4, const float* __restrict__ W5,
              const float* __restrict__ W6, const float* __restrict__ W7,
              short* __restrict__ Wt,
              const int* __restrict__ tgt, int* __restrict__ counts)
{
    const int b = blockIdx.x;
    if (b < MW_BLOCKS) {
        const int wsel = b >> 3;
        const float* W = (wsel == 0) ? W0 : (wsel == 1) ? W1 : (wsel == 2) ? W2 :
                         (wsel == 3) ? W3 : (wsel == 4) ? W4 : (wsel == 5) ? W5 :
                         (wsel == 6) ? W6 : W7;
        const int slot = (b & 7) * 256 + threadIdx.x;
        const int frag = slot >> 6;
        const int lane = slot & 63;
        const int n    = (frag >> 2) * 16 + (lane & 15);
        const int kc   = frag & 3;
        const int quad = lane >> 4;
        const int k0   = kc * 32 + quad * 8;
        s8v v;
#pragma unroll
        for (int j = 0; j < 8; ++j)
            v[j] = (short)f2bf(W[(size_t)(k0 + j) * D + n]);
        *(s8v*)(Wt + (size_t)wsel * W_FRAG_SHORTS + (size_t)slot * 8) = v;
    } else {
        const int e = (b - MW_BLOCKS) * 256 + threadIdx.x;
        if (e < N_EDGES) atomicAdd(&counts[tgt[e]], 1);
    }
}

// ---------------------------------------------------------------------------
// Single-kernel CSR offset build (R8-verified).
// ---------------------------------------------------------------------------
__global__ __launch_bounds__(256)
void csr_scan(const int* __restrict__ counts, int* __restrict__ off,
              int* __restrict__ cursor, int* __restrict__ done_ctr,
              int* __restrict__ chunk_sum)
{
    __shared__ int s[256];
    const int b = blockIdx.x, t = threadIdx.x;
    const int i = b * 256 + t;
    const int v = (i < N_NODES) ? counts[i] : 0;
    s[t] = v;
    __syncthreads();
    for (int d = 1; d < 256; d <<= 1) {
        int tt = (t >= d) ? s[t - d] : 0;
        __syncthreads();
        s[t] += tt;
        __syncthreads();
    }
    const int incl = s[t];

    if (t == 255) {
        __hip_atomic_store(&chunk_sum[b], incl, __ATOMIC_RELAXED, __HIP_MEMORY_SCOPE_AGENT);
        __hip_atomic_fetch_add(done_ctr, 1, __ATOMIC_RELEASE, __HIP_MEMORY_SCOPE_AGENT);
    }
    if (t == 0) {
        while (__hip_atomic_load(done_ctr, __ATOMIC_ACQUIRE, __HIP_MEMORY_SCOPE_AGENT) < NCHUNKS)
            __builtin_amdgcn_s_sleep(8);
    }
    __syncthreads();

    const int pv = (t < b) ? __hip_atomic_load(&chunk_sum[t], __ATOMIC_RELAXED,
                                               __HIP_MEMORY_SCOPE_AGENT) : 0;
    __syncthreads();
    s[t] = pv;
    __syncthreads();
    for (int d = 128; d > 0; d >>= 1) {
        if (t < d) s[t] += s[t + d];
        __syncthreads();
    }
    const int base = s[0];

    if (i < N_NODES) {
        const int excl = base + incl - v;
        off[i]    = excl;
        cursor[i] = excl;
    }
    if (b == 0 && t == 0) off[N_NODES] = N_EDGES;
}

// ---------------------------------------------------------------------------
// 32-row gemm tile building blocks. Per wave: 2 m-tiles x 2 n-tiles, cols
// [w*32, w*32+32). B frags loaded directly from global Wt (L2-hit dwordx4).
// ---------------------------------------------------------------------------
__device__ __forceinline__
void mfma_phase32(const short* As, const short* __restrict__ Wf,
                  int lane, int w, f4v acc[2][2])
{
    s8v bv[2][4];
#pragma unroll
    for (int nt2 = 0; nt2 < 2; ++nt2)
#pragma unroll
        for (int kc = 0; kc < 4; ++kc)
            bv[nt2][kc] = *(const s8v*)(Wf + (((2 * w + nt2) * 4 + kc) * 64 + lane) * 8);
#pragma unroll
    for (int mt = 0; mt < 2; ++mt)
#pragma unroll
        for (int nt2 = 0; nt2 < 2; ++nt2)
            acc[mt][nt2] = (f4v){0.f, 0.f, 0.f, 0.f};
#pragma unroll
    for (int kc = 0; kc < 4; ++kc) {
        const int sl = (lane ^ (kc << 1)) * 8;
        s8v a0 = *(const s8v*)&As[(0 * 4 + kc) * 512 + sl];
        s8v a1 = *(const s8v*)&As[(1 * 4 + kc) * 512 + sl];
#pragma unroll
        for (int nt2 = 0; nt2 < 2; ++nt2) {
            acc[0][nt2] = __builtin_amdgcn_mfma_f32_16x16x32_bf16(a0, bv[nt2][kc], acc[0][nt2], 0, 0, 0);
            acc[1][nt2] = __builtin_amdgcn_mfma_f32_16x16x32_bf16(a1, bv[nt2][kc], acc[1][nt2], 0, 0, 0);
        }
    }
}

__device__ __forceinline__
void c_to_lds32(float* Cs, int lane, int w, const f4v acc[2][2])
{
#pragma unroll
    for (int mt = 0; mt < 2; ++mt) {
        const int r0 = mt * 16 + (lane >> 4) * 4;
#pragma unroll
        for (int nt2 = 0; nt2 < 2; ++nt2) {
            const int col = w * 32 + nt2 * 16 + (lane & 15);
            const int g = col >> 2, jj = col & 3;
#pragma unroll
            for (int i = 0; i < 4; ++i) {
                const int row = r0 + i;
                const int gs  = g ^ (((row >> 2) & 3) << 2);
                Cs[row * 128 + gs * 4 + jj] = acc[mt][nt2][i];
            }
        }
    }
}

// ---------------------------------------------------------------------------
// Fused 4-projection GEMM tile: 32 rows, phases K | QV-joint | S.
// LDS = As 8KB + Cs 16KB + bias 0.5KB = 25.1KB -> 6 blocks/CU LDS-wise
// (vs 48.5KB / 3 blocks before); no B staging, 8 barriers (vs 14).
// X_FP32: read fp32 X and convert during A-stage (layer 1).
// AGG_BF16: skip/agg output packed bf16 (layer 1); else fp32 (layer 2 -> out).
// ---------------------------------------------------------------------------
template<bool X_FP32, bool AGG_BF16>
__device__ __forceinline__
void gemm_tile(int m0, const float* __restrict__ Xf, const short* __restrict__ Xb,
               const short* __restrict__ WtL, const float* __restrict__ bias,
               short* __restrict__ Kb, unsigned int* __restrict__ QV,
               float* __restrict__ AggF, unsigned int* __restrict__ AggB,
               short* As, float* Cs, float* biasS)
{
    const int tid  = threadIdx.x;
    const int lane = tid & 63;
    const int w    = tid >> 6;

    if (tid < 128) biasS[tid] = bias[tid];

    // ---- Stage A (32 rows x 128 k, bf16) fragment-major, swizzled ----
#pragma unroll
    for (int i = 0; i < 2; ++i) {
        const int m   = (tid >> 4) + 16 * i;
        const int oct = tid & 15;
        const int row = m0 + m;
        s8v v = (s8v){0, 0, 0, 0, 0, 0, 0, 0};
        if (row < N_NODES) {
            if (X_FP32) {
                const float* p = Xf + (size_t)row * D + oct * 8;
                float4 a0 = *(const float4*)p;
                float4 a1 = *(const float4*)(p + 4);
                v[0] = (short)f2bf(a0.x); v[1] = (short)f2bf(a0.y);
                v[2] = (short)f2bf(a0.z); v[3] = (short)f2bf(a0.w);
                v[4] = (short)f2bf(a1.x); v[5] = (short)f2bf(a1.y);
                v[6] = (short)f2bf(a1.z); v[7] = (short)f2bf(a1.w);
            } else {
                v = *(const s8v*)(Xb + (size_t)row * D + oct * 8);
            }
        }
        const int kc = oct >> 2, quad = oct & 3;
        const int frag = (m >> 4) * 4 + kc;
        const int slot = ((m & 15) + 16 * quad) ^ (kc << 1);
        *(s8v*)&As[frag * 512 + slot * 8] = v;
    }

    f4v acc[2][2], accV[2][2];
    __syncthreads();

    // ================= Phase K (sel 0) =================
    mfma_phase32(As, WtL + 0 * W_FRAG_SHORTS, lane, w, acc);
    c_to_lds32(Cs, lane, w, acc);
    __syncthreads();
#pragma unroll
    for (int j = 0; j < 4; ++j) {
        const int c   = tid + 256 * j;
        const int row = c >> 5, gg = c & 31;
        const int gs  = gg ^ (((row >> 2) & 3) << 2);
        const f4v vv  = *(const f4v*)&Cs[row * 128 + gs * 4];
        const int grow = m0 + row;
        if (grow < N_NODES) {
            uint2* kp = (uint2*)((unsigned int*)Kb + (size_t)grow * 64 + gg * 2);
            *kp = make_uint2(packbf(vv[0], vv[1]), packbf(vv[2], vv[3]));
        }
    }
    __syncthreads();

    // ================= Phase QV (sel 1 + 2, joint epilogue) =================
    mfma_phase32(As, WtL + 1 * W_FRAG_SHORTS, lane, w, acc);   // Q
    mfma_phase32(As, WtL + 2 * W_FRAG_SHORTS, lane, w, accV);  // V (no barrier needed)
    c_to_lds32(Cs, lane, w, acc);        // Q roundtrip
    __syncthreads();
    unsigned int qp0[4], qp1[4];
#pragma unroll
    for (int j = 0; j < 4; ++j) {
        const int c   = tid + 256 * j;
        const int row = c >> 5, gg = c & 31;
        const int gs  = gg ^ (((row >> 2) & 3) << 2);
        const f4v vv  = *(const f4v*)&Cs[row * 128 + gs * 4];
        qp0[j] = packbf(vv[0], vv[1]);
        qp1[j] = packbf(vv[2], vv[3]);
    }
    __syncthreads();
    c_to_lds32(Cs, lane, w, accV);       // V roundtrip
    __syncthreads();
#pragma unroll
    for (int j = 0; j < 4; ++j) {
        const int c   = tid + 256 * j;
        const int row = c >> 5, gg = c & 31;
        const int gs  = gg ^ (((row >> 2) & 3) << 2);
        const f4v vv  = *(const f4v*)&Cs[row * 128 + gs * 4];
        const int grow = m0 + row;
        if (grow < N_NODES) {
            uint4* qvp = (uint4*)(QV + (size_t)grow * 128 + gg * 4);
            *qvp = make_uint4(qp0[j], packbf(vv[0], vv[1]),
                              qp1[j], packbf(vv[2], vv[3]));
        }
    }
    __syncthreads();

    // ================= Phase S (sel 3, skip + bias) =================
    mfma_phase32(As, WtL + 3 * W_FRAG_SHORTS, lane, w, acc);
    c_to_lds32(Cs, lane, w, acc);
    __syncthreads();
#pragma unroll
    for (int j = 0; j < 4; ++j) {
        const int c   = tid + 256 * j;
        const int row = c >> 5, gg = c & 31;
        const int gs  = gg ^ (((row >> 2) & 3) << 2);
        const f4v vv  = *(const f4v*)&Cs[row * 128 + gs * 4];
        const int grow = m0 + row;
        if (grow >= N_NODES) continue;
        const float4 bv = *(const float4*)&biasS[gg * 4];
        const float o0 = vv[0] + bv.x, o1 = vv[1] + bv.y;
        const float o2 = vv[2] + bv.z, o3 = vv[3] + bv.w;
        if (AGG_BF16) {
            uint2* ap = (uint2*)(AggB + (size_t)grow * 64 + gg * 2);
            *ap = make_uint2(packbf(o0, o1), packbf(o2, o3));
        } else {
            *(float4*)&AggF[(size_t)grow * D + gg * 4] = make_float4(o0, o1, o2, o3);
        }
    }
}

// ---------------------------------------------------------------------------
// Layer-1 GEMM (fp32 x input, bf16 agg out) + fused edge scatter blocks.
// ---------------------------------------------------------------------------
__global__ __launch_bounds__(256, 4)
void gemm1_scatter(const float* __restrict__ X, const short* __restrict__ WtL,
                   const float* __restrict__ bias,
                   short* __restrict__ Kb, unsigned int* __restrict__ QV,
                   unsigned int* __restrict__ AggB,
                   const int* __restrict__ src, const int* __restrict__ tgt,
                   int* __restrict__ cursor, int* __restrict__ es)
{
    __shared__ __align__(16) short As[4096];    // 8 KB
    __shared__ __align__(16) float Cs[4096];    // 16 KB
    __shared__ __align__(16) float biasS[128];  // 0.5 KB

    if (blockIdx.x < NBLK32) {
        gemm_tile<true, true>(blockIdx.x * 32, X, nullptr, WtL, bias,
                              Kb, QV, nullptr, AggB, As, Cs, biasS);
    } else {
        const int e = (blockIdx.x - NBLK32) * 256 + threadIdx.x;
        if (e < N_EDGES) {
            int pos = atomicAdd(&cursor[tgt[e]], 1);
            es[pos] = src[e];
        }
    }
}

// Layer-2 GEMM (bf16 relu(h) input, fp32 agg -> d_out).
__global__ __launch_bounds__(256, 4)
void gemm2(const short* __restrict__ Hb, const short* __restrict__ WtL,
           const float* __restrict__ bias,
           short* __restrict__ Kb, unsigned int* __restrict__ QV,
           float* __restrict__ AggF)
{
    __shared__ __align__(16) short As[4096];
    __shared__ __align__(16) float Cs[4096];
    __shared__ __align__(16) float biasS[128];
    gemm_tile<false, false>(blockIdx.x * 32, nullptr, Hb, WtL, bias,
                            Kb, QV, AggF, nullptr, As, Cs, biasS);
}

// ---------------------------------------------------------------------------
// Atomic-free per-node aggregation. One wave per node. 8-wide gather stage:
// one lane-parallel es load + readlane (8 uint2 gathers in flight).
// FIRST: Skip = bf16 agg1; out = bf16 relu -> Hb. Else: Skip = fp32 (d_out RMW).
// ---------------------------------------------------------------------------
template<bool FIRST>
__global__ __launch_bounds__(256)
void node_agg(const int* __restrict__ off, const int* __restrict__ es,
              const short* __restrict__ K, const unsigned int* __restrict__ QV,
              const void* __restrict__ Skip, float* __restrict__ OutF,
              unsigned int* __restrict__ Hb)
{
    const int lane = threadIdx.x & 63;
    const int t    = __builtin_amdgcn_readfirstlane(blockIdx.x * 4 + (threadIdx.x >> 6));

    const unsigned int ku = ((const unsigned int*)K)[(size_t)t * 64 + lane];
    const float kx = bflo(ku), ky = bfhi(ku);

    float skx, sky;
    if (FIRST) {
        const unsigned int su = ((const unsigned int*)Skip)[(size_t)t * 64 + lane];
        skx = bflo(su); sky = bfhi(su);
    } else {
        const float2 s2 = ((const float2*)Skip)[(size_t)t * 64 + lane];
        skx = s2.x; sky = s2.y;
    }

    float ax = 0.f, ay = 0.f, bx = 0.f, by = 0.f;
    const int e0 = __builtin_amdgcn_readfirstlane(off[t]);
    const int e1 = __builtin_amdgcn_readfirstlane(off[t + 1]);

    int e = e0;
    for (; e + 8 <= e1; e += 8) {
        const int sv = es[e + (lane & 7)];
        uint2 g[8];
#pragma unroll
        for (int u = 0; u < 8; ++u) {
            const int s = __builtin_amdgcn_readlane(sv, u);
            g[u] = ((const uint2*)(QV + (size_t)s * 128))[lane];
        }
#pragma unroll
        for (int u = 0; u < 8; ++u) {
            if (u & 1) {
                bx += bflo(g[u].y) * sigm(kx + bflo(g[u].x));
                by += bfhi(g[u].y) * sigm(ky + bfhi(g[u].x));
            } else {
                ax += bflo(g[u].y) * sigm(kx + bflo(g[u].x));
                ay += bfhi(g[u].y) * sigm(ky + bfhi(g[u].x));
            }
        }
    }
    if (e + 4 <= e1) {
        const int sv = es[e + (lane & 3)];
        uint2 g[4];
#pragma unroll
        for (int u = 0; u < 4; ++u) {
            const int s = __builtin_amdgcn_readlane(sv, u);
            g[u] = ((const uint2*)(QV + (size_t)s * 128))[lane];
        }
#pragma unroll
        for (int u = 0; u < 4; ++u) {
            if (u & 1) {
                bx += bflo(g[u].y) * sigm(kx + bflo(g[u].x));
                by += bfhi(g[u].y) * sigm(ky + bfhi(g[u].x));
            } else {
                ax += bflo(g[u].y) * sigm(kx + bflo(g[u].x));
                ay += bfhi(g[u].y) * sigm(ky + bfhi(g[u].x));
            }
        }
        e += 4;
    }
    for (; e < e1; ++e) {
        const int s0 = __builtin_amdgcn_readfirstlane(es[e]);
        const uint2 g0 = ((const uint2*)(QV + (size_t)s0 * 128))[lane];
        ax += bflo(g0.y) * sigm(kx + bflo(g0.x));
        ay += bfhi(g0.y) * sigm(ky + bfhi(g0.x));
    }

    const float rx = skx + ax + bx;
    const float ry = sky + ay + by;

    if (FIRST) {
        Hb[(size_t)t * 64 + lane] = packbf(fmaxf(rx, 0.f), fmaxf(ry, 0.f));
    } else {
        ((float2*)OutF)[(size_t)t * 64 + lane] = make_float2(rx, ry);
    }
}

extern "C" void kernel_launch(void* const* d_in, const int* in_sizes, int n_in,
                              void* d_out, int out_size, void* d_ws, size_t ws_size,
                              hipStream_t stream)
{
    const float* x   = (const float*)d_in[0];
    const int*   ei  = (const int*)d_in[1];
    const float* Wk1 = (const float*)d_in[2];
    const float* Wq1 = (const float*)d_in[3];
    const float* Wv1 = (const float*)d_in[4];
    const float* Ws1 = (const float*)d_in[5];
    const float* b1  = (const float*)d_in[6];
    const float* Wk2 = (const float*)d_in[7];
    const float* Wq2 = (const float*)d_in[8];
    const float* Wv2 = (const float*)d_in[9];
    const float* Ws2 = (const float*)d_in[10];
    const float* b2  = (const float*)d_in[11];

    const int* src = ei;
    const int* tgt = ei + N_EDGES;

    const size_t nd = (size_t)N_NODES * D;   // 6.4M elements
    short* kb   = (short*)d_ws;              // bf16 K                (nd shorts)
    short* qv   = kb + nd;                   // bf16 QV interleaved   (2*nd)
    short* hb   = qv + 2 * nd;               // bf16 relu(h)          (nd)
    short* ag1  = hb + nd;                   // bf16 x@Ws1+b1         (nd)
    short* wt   = ag1 + nd;                  // 8 * 16384 shorts
    int* counts    = (int*)(wt + 8 * W_FRAG_SHORTS);   // N_NODES
    int* done_ctr  = counts + N_NODES;                 // 1 (+1 pad)
    int* off       = counts + N_NODES + 2;             // N_NODES + 1
    int* cursor    = off + N_NODES + 1;                // N_NODES
    int* es        = cursor + N_NODES;                 // N_EDGES
    int* chunk_sum = es + N_EDGES;                     // NCHUNKS
    float* out = (float*)d_out;

    hipMemsetAsync(counts, 0, (N_NODES + 2) * sizeof(int), stream);
    prep_all<<<PREP_BLOCKS, 256, 0, stream>>>(Wk1, Wq1, Wv1, Ws1, Wk2, Wq2, Wv2, Ws2,
                                              wt, tgt, counts);
    csr_scan<<<NCHUNKS, 256, 0, stream>>>(counts, off, cursor, done_ctr, chunk_sum);

    // Layer 1 (+ fused edge scatter)
    gemm1_scatter<<<NBLK32 + HIST_BLOCKS, 256, 0, stream>>>(
        x, wt, b1, kb, (unsigned int*)qv, (unsigned int*)ag1, src, tgt, cursor, es);
    node_agg<true><<<N_NODES / 4, 256, 0, stream>>>(off, es, kb, (const unsigned int*)qv,
                                                    ag1, nullptr, (unsigned int*)hb);

    // Layer 2
    gemm2<<<NBLK32, 256, 0, stream>>>(hb, wt + 4 * W_FRAG_SHORTS, b2,
                                      kb, (unsigned int*)qv, out);
    node_agg<false><<<N_NODES / 4, 256, 0, stream>>>(off, es, kb, (const unsigned int*)qv,
                                                     out, out, nullptr);
}